// Round 6
// baseline (207.720 us; speedup 1.0000x reference)
//
#include <hip/hip_runtime.h>
#include <hip/hip_bf16.h>

// ---------- constants (problem-fixed) ----------
#define NNODES 10000
#define NEDGES 80000
#define OBS    128
#define HID    1024
#define ACTD   8
#define NGR    64

typedef __bf16 bf16x8 __attribute__((ext_vector_type(8)));
typedef float  f32x4  __attribute__((ext_vector_type(4)));

__device__ __forceinline__ ushort f2b(float f) {       // f32 -> bf16 (RNE)
    union { float f; unsigned int i; } v; v.f = f;
    unsigned int lsb = (v.i >> 16) & 1u;
    unsigned int r = v.i + 0x7fffu + lsb;
    return (ushort)(r >> 16);
}
__device__ __forceinline__ float b2f(ushort u) {
    union { unsigned int i; float f; } v; v.i = ((unsigned int)u) << 16; return v.f;
}
__device__ __forceinline__ int cix(int v, int hi) {    // clamp index to [0, hi)
    return v < 0 ? 0 : (v >= hi ? hi - 1 : v);
}

// ---------- init: zero accumulators (ws is re-poisoned 0xAA before each call) ----------
__global__ void k_init(int* degi, float* zacc, float* zagg, float* pool, float* cnt, int n) {
    int i = blockIdx.x * 256 + threadIdx.x;
    if (i < n) degi[i] = 0;
    if (i < n * ACTD) { zacc[i] = 0.0f; zagg[i] = 0.0f; }
    if (i < NGR * ACTD) pool[i] = 0.0f;
    if (i < NGR) cnt[i] = 0.0f;
}

__global__ void k_count(const int* __restrict__ dst, int* degi, int e) {
    int i = blockIdx.x * 256 + threadIdx.x;
    if (i < e) atomicAdd(&degi[cix(dst[i], NNODES)], 1);
}

// single-block exclusive prefix scan over degi -> rowptr (N+1) + cursor copy + dinv
__global__ __launch_bounds__(1024) void k_scan(const int* __restrict__ degi,
                                               int* rowptr, int* cursor, float* dinv) {
    __shared__ int sums[1024];
    int t = threadIdx.x;
    int base = t * 10;                                   // 10240 >= NNODES
    int local[10];
    int s = 0;
    #pragma unroll
    for (int k = 0; k < 10; ++k) {
        int i = base + k;
        int v = 0;
        if (i < NNODES) {
            v = degi[i];
            dinv[i] = rsqrtf((float)(v + 1));            // +1 self-loop
        }
        local[k] = s; s += v;
    }
    sums[t] = s;
    __syncthreads();
    int own = s;
    for (int off = 1; off < 1024; off <<= 1) {
        int v = (t >= off) ? sums[t - off] : 0;
        __syncthreads();
        sums[t] += v;
        __syncthreads();
    }
    int excl = sums[t] - own;
    #pragma unroll
    for (int k = 0; k < 10; ++k) {
        int i = base + k;
        if (i < NNODES) { rowptr[i] = excl + local[k]; cursor[i] = excl + local[k]; }
    }
    if (t == 1023) rowptr[NNODES] = sums[1023];
}

// bucket edges by dst: sorted src + dst + coef
__global__ void k_fill(const int* __restrict__ src, const int* __restrict__ dst,
                       const float* __restrict__ dinv, int* cursor,
                       int* __restrict__ esrc, int* __restrict__ edst,
                       float* __restrict__ coefs, int e) {
    int i = blockIdx.x * 256 + threadIdx.x;
    if (i >= e) return;
    int s = cix(src[i], NNODES), d = cix(dst[i], NNODES);
    int pos = atomicAdd(&cursor[d], 1);
    esrc[pos] = s;
    edst[pos] = d;
    coefs[pos] = dinv[s] * dinv[d];
}

// transpose+cast W1 [OBS x HID] f32 -> Wt1 [HID x OBS] bf16
__global__ void k_transpose_cast(const float* __restrict__ in, ushort* __restrict__ out,
                                 int R, int C) {
    __shared__ float tile[32][33];
    int bx = blockIdx.x * 32, by = blockIdx.y * 32;
    int tx = threadIdx.x & 31, ty = threadIdx.x >> 5;
    #pragma unroll
    for (int i = 0; i < 32; i += 8)
        tile[ty + i][tx] = in[(size_t)(by + ty + i) * C + bx + tx];
    __syncthreads();
    #pragma unroll
    for (int i = 0; i < 32; i += 8)
        out[(size_t)(bx + ty + i) * R + by + tx] = f2b(tile[tx][ty + i]);
}

// rows 0..HID-1: M2bf[i][j] = bf16( sum_k W2[i][k]*Wl[k][j] )
// row HID:       b2l[j] = sum_k b2[k]*Wl[k][j] + bl[j]
__global__ void k_m2(const float* __restrict__ W2, const float* __restrict__ Wl,
                     const float* __restrict__ b2, const float* __restrict__ bl,
                     ushort* __restrict__ M2bf, float* __restrict__ b2l) {
    int wvid = (blockIdx.x * 256 + threadIdx.x) >> 6;
    int lane = threadIdx.x & 63;
    if (wvid > HID) return;
    const float* row = (wvid == HID) ? b2 : (W2 + (size_t)wvid * HID);
    float acc[ACTD];
    #pragma unroll
    for (int j = 0; j < ACTD; ++j) acc[j] = 0.0f;
    for (int it = 0; it < HID / 64; ++it) {
        int k = it * 64 + lane;
        float w2v = row[k];
        float4 a = *(const float4*)(Wl + (size_t)k * ACTD);
        float4 b = *(const float4*)(Wl + (size_t)k * ACTD + 4);
        acc[0] += w2v * a.x; acc[1] += w2v * a.y; acc[2] += w2v * a.z; acc[3] += w2v * a.w;
        acc[4] += w2v * b.x; acc[5] += w2v * b.y; acc[6] += w2v * b.z; acc[7] += w2v * b.w;
    }
    #pragma unroll
    for (int off = 32; off > 0; off >>= 1)
        #pragma unroll
        for (int j = 0; j < ACTD; ++j)
            acc[j] += __shfl_down(acc[j], off);
    if (lane == 0) {
        if (wvid == HID) {
            #pragma unroll
            for (int j = 0; j < ACTD; ++j) b2l[j] = acc[j] + bl[j];
        } else {
            #pragma unroll
            for (int j = 0; j < ACTD; ++j) M2bf[wvid * ACTD + j] = f2b(acc[j]);
        }
    }
}

// ---------- layer-1 aggregation: CSR gather, one wave per node ----------
__global__ void k_aggx(const float* __restrict__ x, const float* __restrict__ dinv,
                       const int* __restrict__ rowptr, const int* __restrict__ esrc,
                       const float* __restrict__ coefs, ushort* __restrict__ aggbf, int n) {
    int wv = (blockIdx.x * 256 + threadIdx.x) >> 6;
    int lane = threadIdx.x & 63;
    if (wv >= n) return;
    float d = dinv[wv], d2 = d * d;
    float2 xv = *(const float2*)(x + (size_t)wv * OBS + lane * 2);
    float v0 = xv.x * d2, v1 = xv.y * d2;
    int e0 = rowptr[wv], e1 = rowptr[wv + 1];
    for (int e = e0; e < e1; ++e) {                      // wave-uniform loop
        int s = esrc[e];
        float c = coefs[e];
        float2 sv = *(const float2*)(x + (size_t)s * OBS + lane * 2);
        v0 += sv.x * c; v1 += sv.y * c;
    }
    ushort2 o; o.x = f2b(v0); o.y = f2b(v1);
    *(ushort2*)(aggbf + (size_t)wv * OBS + lane * 2) = o;
}

// ---------- fused GEMM1 + relu + MFMA epilogue (@M2) -> zacc ----------
__global__ __launch_bounds__(256) void k_gemm1_fused(const ushort* __restrict__ A,
                                                     const ushort* __restrict__ Bt,
                                                     const float* __restrict__ bias,
                                                     const ushort* __restrict__ M2bf,
                                                     float* __restrict__ zacc,
                                                     int M) {
    __shared__ ushort buf[128 * 136 + 16 * 128];         // 38912 B
    ushort* As    = buf;
    ushort* Bs    = buf + 4096;
    ushort* stage = buf;
    ushort* M2t   = buf + 128 * 136;

    const int t = threadIdx.x;
    const int bm = blockIdx.x, bn = blockIdx.y;
    const int lane = t & 63, wv = t >> 6;
    const int wm = (wv & 1) * 64, wn = (wv >> 1) * 64;
    const int l16 = lane & 15, kg = (lane >> 4) * 8;
    const int r0 = t >> 2;
    const int c0 = (t & 3) << 3;

    if (t < 128) {
        ushort4 a = *(const ushort4*)(M2bf + (size_t)(bn * 128 + t) * ACTD);
        ushort4 b = *(const ushort4*)(M2bf + (size_t)(bn * 128 + t) * ACTD + 4);
        M2t[0 * 128 + t] = a.x; M2t[1 * 128 + t] = a.y;
        M2t[2 * 128 + t] = a.z; M2t[3 * 128 + t] = a.w;
        M2t[4 * 128 + t] = b.x; M2t[5 * 128 + t] = b.y;
        M2t[6 * 128 + t] = b.z; M2t[7 * 128 + t] = b.w;
        #pragma unroll
        for (int j = 8; j < 16; ++j) M2t[j * 128 + t] = 0;
    }

    f32x4 acc[4][4];
    #pragma unroll
    for (int i = 0; i < 4; ++i)
        #pragma unroll
        for (int j = 0; j < 4; ++j)
            acc[i][j] = (f32x4){0.f, 0.f, 0.f, 0.f};

    for (int kt = 0; kt < OBS; kt += 32) {
        if (kt) __syncthreads();
        #pragma unroll
        for (int rd = 0; rd < 2; ++rd) {
            int r = r0 + rd * 64;
            int gr = bm * 128 + r;
            uint4 va = make_uint4(0, 0, 0, 0);
            if (gr < M) va = *(const uint4*)(A + (size_t)gr * OBS + kt + c0);
            *(uint4*)(As + r * 32 + c0) = va;
            int gn = bn * 128 + r;
            uint4 vb = *(const uint4*)(Bt + (size_t)gn * OBS + kt + c0);
            *(uint4*)(Bs + r * 32 + c0) = vb;
        }
        __syncthreads();
        bf16x8 af[4], bfr[4];
        #pragma unroll
        for (int i = 0; i < 4; ++i)
            af[i] = *(const bf16x8*)(As + (wm + i * 16 + l16) * 32 + kg);
        #pragma unroll
        for (int j = 0; j < 4; ++j)
            bfr[j] = *(const bf16x8*)(Bs + (wn + j * 16 + l16) * 32 + kg);
        #pragma unroll
        for (int i = 0; i < 4; ++i)
            #pragma unroll
            for (int j = 0; j < 4; ++j)
                acc[i][j] = __builtin_amdgcn_mfma_f32_16x16x32_bf16(af[i], bfr[j], acc[i][j], 0, 0, 0);
    }
    __syncthreads();                                     // As/Bs dead; stage takes over

    #pragma unroll
    for (int i = 0; i < 4; ++i) {
        int rowb = wm + i * 16 + (lane >> 4) * 4;
        #pragma unroll
        for (int j = 0; j < 4; ++j) {
            int col = wn + j * 16 + l16;
            float bj = bias[bn * 128 + col];
            #pragma unroll
            for (int r = 0; r < 4; ++r)
                stage[(rowb + r) * 136 + col] = f2b(fmaxf(acc[i][j][r] + bj, 0.0f));
        }
    }
    __syncthreads();

    #pragma unroll
    for (int st = 0; st < 2; ++st) {
        int row0 = wv * 32 + st * 16;
        f32x4 z = (f32x4){0.f, 0.f, 0.f, 0.f};
        #pragma unroll
        for (int kt = 0; kt < 128; kt += 32) {
            bf16x8 a = *(const bf16x8*)(stage + (row0 + l16) * 136 + kt + kg);
            bf16x8 b = *(const bf16x8*)(M2t + l16 * 128 + kt + kg);
            z = __builtin_amdgcn_mfma_f32_16x16x32_bf16(a, b, z, 0, 0, 0);
        }
        if (l16 < ACTD) {
            int rowb = bm * 128 + row0 + (lane >> 4) * 4;
            #pragma unroll
            for (int r = 0; r < 4; ++r)
                if (rowb + r < M)
                    atomicAdd(&zacc[(size_t)(rowb + r) * ACTD + l16], z[r]);
        }
    }
}

// ---------- layer-2-collapsed aggregation: edge-parallel scatter into zagg ----------
__global__ void k_zagg_edges(const int* __restrict__ esrc, const int* __restrict__ edst,
                             const float* __restrict__ coefs, const float* __restrict__ zacc,
                             float* __restrict__ zagg, int e) {
    int idx = blockIdx.x * 256 + threadIdx.x;            // e*ACTD
    if (idx >= e * ACTD) return;
    int ed = idx >> 3, j = idx & 7;
    int s = esrc[ed], d = edst[ed];
    atomicAdd(&zagg[(size_t)d * ACTD + j], coefs[ed] * zacc[(size_t)s * ACTD + j]);
}

// ---------- self-term + tanh + global mean pool ----------
__global__ void k_pool(const float* __restrict__ zacc, const float* __restrict__ zagg,
                       const float* __restrict__ dinv, const float* __restrict__ b2l,
                       const int* __restrict__ batch, float* __restrict__ pool,
                       float* __restrict__ cnt, int n) {
    int idx = blockIdx.x * 256 + threadIdx.x;            // n*ACTD
    if (idx >= n * ACTD) return;
    int i = idx >> 3, j = idx & 7;
    float d = dinv[i];
    float v = zacc[idx] * d * d + zagg[idx];
    float tz = tanhf(v + b2l[j]);
    int g = cix(batch[i], NGR);
    atomicAdd(&pool[g * ACTD + j], tz);
    if (j == 0) atomicAdd(&cnt[g], 1.0f);
}

__global__ void k_final(const float* __restrict__ pool, const float* __restrict__ cnt,
                        float* __restrict__ out, int total) {
    int i = blockIdx.x * 256 + threadIdx.x;
    if (i < total) out[i] = pool[i] / fmaxf(cnt[i >> 3], 1.0f);
}

// ---------- launch ----------
extern "C" void kernel_launch(void* const* d_in, const int* in_sizes, int n_in,
                              void* d_out, int out_size, void* d_ws, size_t ws_size,
                              hipStream_t stream) {
    const float* x   = (const float*)d_in[0];
    const int*   ei  = (const int*)d_in[1];
    const int*   bat = (const int*)d_in[2];
    const float* W1  = (const float*)d_in[3];
    const float* b1  = (const float*)d_in[4];
    const float* W2  = (const float*)d_in[5];
    const float* b2v = (const float*)d_in[6];
    const float* Wl  = (const float*)d_in[7];
    const float* bl  = (const float*)d_in[8];
    float* out = (float*)d_out;

    const int N = NNODES, E = NEDGES;
    const int* src = ei;
    const int* dst = ei + E;

    // workspace layout — ~5.3 MB total
    char* ws = (char*)d_ws;
    size_t off = 0;
    float*  pool   = (float*)(ws + off); off += 2048;
    float*  cnt    = (float*)(ws + off); off += 256;
    float*  dinv   = (float*)(ws + off); off += 40192;                   // N f32
    int*    degi   = (int*)(ws + off);   off += 40192;                   // N i32
    int*    rowptr = (int*)(ws + off);   off += 40448;                   // N+1 i32
    int*    cursor = (int*)(ws + off);   off += 40192;                   // N i32
    int*    esrc   = (int*)(ws + off);   off += (size_t)E * 4;           // 320000
    int*    edst   = (int*)(ws + off);   off += (size_t)E * 4;           // 320000
    float*  coefs  = (float*)(ws + off); off += (size_t)E * 4;           // 320000
    float*  b2l    = (float*)(ws + off); off += 256;
    ushort* M2bf   = (ushort*)(ws + off); off += (size_t)HID * ACTD * 2; // 16384
    ushort* Wt1    = (ushort*)(ws + off); off += (size_t)HID * OBS * 2;  // 262144
    float*  zacc   = (float*)(ws + off); off += (size_t)N * ACTD * 4;    // 320000
    float*  zagg   = (float*)(ws + off); off += (size_t)N * ACTD * 4;    // 320000
    ushort* aggbf  = (ushort*)(ws + off); off += (size_t)N * OBS * 2;    // 2560000

    // 1. degree + dinv + CSR build
    k_init<<<(N * ACTD + 255) / 256, 256, 0, stream>>>(degi, zacc, zagg, pool, cnt, N);
    k_count<<<(E + 255) / 256, 256, 0, stream>>>(dst, degi, E);
    k_scan<<<1, 1024, 0, stream>>>(degi, rowptr, cursor, dinv);
    k_fill<<<(E + 255) / 256, 256, 0, stream>>>(src, dst, dinv, cursor, esrc, edst, coefs, E);

    // 2. weight prep
    k_transpose_cast<<<dim3(HID / 32, OBS / 32), 256, 0, stream>>>(W1, Wt1, OBS, HID);
    k_m2<<<((HID + 1) * 64 + 255) / 256, 256, 0, stream>>>(W2, Wl, b2v, bl, M2bf, b2l);

    // 3. layer-1 aggregation (gather) -> bf16
    k_aggx<<<(N * 64 + 255) / 256, 256, 0, stream>>>(x, dinv, rowptr, esrc, coefs, aggbf, N);

    // 4. fused GEMM1 + relu + @M2 -> zacc
    k_gemm1_fused<<<dim3((N + 127) / 128, HID / 128), 256, 0, stream>>>(
        aggbf, Wt1, b1, M2bf, zacc, N);

    // 5. aggregate z (edge-parallel scatter), tanh, pool, finalize
    k_zagg_edges<<<(E * ACTD + 255) / 256, 256, 0, stream>>>(esrc, edst, coefs, zacc, zagg, E);
    k_pool<<<(N * ACTD + 255) / 256, 256, 0, stream>>>(zacc, zagg, dinv, b2l, bat, pool, cnt, N);
    k_final<<<2, 256, 0, stream>>>(pool, cnt, out, NGR * ACTD);
}

// Round 7
// 139.085 us; speedup vs baseline: 1.4935x; 1.4935x over previous
//
#include <hip/hip_runtime.h>
#include <hip/hip_bf16.h>

// ---------- constants (problem-fixed) ----------
#define NNODES 10000
#define NEDGES 80000
#define OBS    128
#define HID    1024
#define ACTD   8
#define NGR    64

typedef __bf16 bf16x8 __attribute__((ext_vector_type(8)));
typedef float  f32x4  __attribute__((ext_vector_type(4)));

__device__ __forceinline__ ushort f2b(float f) {       // f32 -> bf16 (RNE)
    union { float f; unsigned int i; } v; v.f = f;
    unsigned int lsb = (v.i >> 16) & 1u;
    unsigned int r = v.i + 0x7fffu + lsb;
    return (ushort)(r >> 16);
}
__device__ __forceinline__ float b2f(ushort u) {
    union { unsigned int i; float f; } v; v.i = ((unsigned int)u) << 16; return v.f;
}
__device__ __forceinline__ int cix(int v, int hi) {    // clamp index to [0, hi)
    return v < 0 ? 0 : (v >= hi ? hi - 1 : v);
}

// ---------- init: zero accumulators (ws is re-poisoned 0xAA before each call) ----------
__global__ void k_init(int* degi, float* zacc, float* pool, float* cnt, int n) {
    int i = blockIdx.x * 256 + threadIdx.x;
    if (i < n) degi[i] = 0;
    if (i < n * ACTD) zacc[i] = 0.0f;
    if (i < NGR * ACTD) pool[i] = 0.0f;
    if (i < NGR) cnt[i] = 0.0f;
}

__global__ void k_count(const int* __restrict__ dst, int* degi, int e) {
    int i = blockIdx.x * 256 + threadIdx.x;
    if (i < e) atomicAdd(&degi[cix(dst[i], NNODES)], 1);
}

// single-block exclusive prefix scan over degi -> rowptr (N+1) + cursor copy + dinv
__global__ __launch_bounds__(1024) void k_scan(const int* __restrict__ degi,
                                               int* rowptr, int* cursor, float* dinv) {
    __shared__ int sums[1024];
    int t = threadIdx.x;
    int base = t * 10;                                   // 10240 >= NNODES
    int local[10];
    int s = 0;
    #pragma unroll
    for (int k = 0; k < 10; ++k) {
        int i = base + k;
        int v = 0;
        if (i < NNODES) {
            v = degi[i];
            dinv[i] = rsqrtf((float)(v + 1));            // +1 self-loop
        }
        local[k] = s; s += v;
    }
    sums[t] = s;
    __syncthreads();
    int own = s;
    for (int off = 1; off < 1024; off <<= 1) {
        int v = (t >= off) ? sums[t - off] : 0;
        __syncthreads();
        sums[t] += v;
        __syncthreads();
    }
    int excl = sums[t] - own;
    #pragma unroll
    for (int k = 0; k < 10; ++k) {
        int i = base + k;
        if (i < NNODES) { rowptr[i] = excl + local[k]; cursor[i] = excl + local[k]; }
    }
    if (t == 1023) rowptr[NNODES] = sums[1023];
}

// bucket edges by dst: sorted src + coef
__global__ void k_fill(const int* __restrict__ src, const int* __restrict__ dst,
                       const float* __restrict__ dinv, int* cursor,
                       int* __restrict__ esrc, float* __restrict__ coefs, int e) {
    int i = blockIdx.x * 256 + threadIdx.x;
    if (i >= e) return;
    int s = cix(src[i], NNODES), d = cix(dst[i], NNODES);
    int pos = atomicAdd(&cursor[d], 1);
    esrc[pos] = s;
    coefs[pos] = dinv[s] * dinv[d];
}

// fused weight prep:
//  blocks [0,128):   transpose+cast W1 [OBS x HID] -> Wt1 [HID x OBS] bf16
//  blocks [128,385): M2bf[i][:] = bf16(W2[i,:] @ Wl)  (+ row HID -> b2l = b2@Wl + bl)
__global__ __launch_bounds__(256) void k_weights(const float* __restrict__ W1,
                                                 const float* __restrict__ W2,
                                                 const float* __restrict__ Wl,
                                                 const float* __restrict__ b2,
                                                 const float* __restrict__ bl,
                                                 ushort* __restrict__ Wt1,
                                                 ushort* __restrict__ M2bf,
                                                 float* __restrict__ b2l) {
    int blk = blockIdx.x;
    if (blk < 128) {
        __shared__ float tile[32][33];
        int bx = (blk & 31) * 32, by = (blk >> 5) * 32;  // bx over HID, by over OBS
        int tx = threadIdx.x & 31, ty = threadIdx.x >> 5;
        #pragma unroll
        for (int i = 0; i < 32; i += 8)
            tile[ty + i][tx] = W1[(size_t)(by + ty + i) * HID + bx + tx];
        __syncthreads();
        #pragma unroll
        for (int i = 0; i < 32; i += 8)
            Wt1[(size_t)(bx + ty + i) * OBS + by + tx] = f2b(tile[tx][ty + i]);
        return;
    }
    int wvid = ((blk - 128) * 256 + (int)threadIdx.x) >> 6;
    int lane = threadIdx.x & 63;
    if (wvid > HID) return;
    const float* row = (wvid == HID) ? b2 : (W2 + (size_t)wvid * HID);
    float acc[ACTD];
    #pragma unroll
    for (int j = 0; j < ACTD; ++j) acc[j] = 0.0f;
    for (int it = 0; it < HID / 64; ++it) {
        int k = it * 64 + lane;
        float w2v = row[k];
        float4 a = *(const float4*)(Wl + (size_t)k * ACTD);
        float4 b = *(const float4*)(Wl + (size_t)k * ACTD + 4);
        acc[0] += w2v * a.x; acc[1] += w2v * a.y; acc[2] += w2v * a.z; acc[3] += w2v * a.w;
        acc[4] += w2v * b.x; acc[5] += w2v * b.y; acc[6] += w2v * b.z; acc[7] += w2v * b.w;
    }
    #pragma unroll
    for (int off = 32; off > 0; off >>= 1)
        #pragma unroll
        for (int j = 0; j < ACTD; ++j)
            acc[j] += __shfl_down(acc[j], off);
    if (lane == 0) {
        if (wvid == HID) {
            #pragma unroll
            for (int j = 0; j < ACTD; ++j) b2l[j] = acc[j] + bl[j];
        } else {
            #pragma unroll
            for (int j = 0; j < ACTD; ++j) M2bf[wvid * ACTD + j] = f2b(acc[j]);
        }
    }
}

// ---------- layer-1 aggregation: CSR gather, one wave per node ----------
__global__ void k_aggx(const float* __restrict__ x, const float* __restrict__ dinv,
                       const int* __restrict__ rowptr, const int* __restrict__ esrc,
                       const float* __restrict__ coefs, ushort* __restrict__ aggbf, int n) {
    int wv = (blockIdx.x * 256 + threadIdx.x) >> 6;
    int lane = threadIdx.x & 63;
    if (wv >= n) return;
    float d = dinv[wv], d2 = d * d;
    float2 xv = *(const float2*)(x + (size_t)wv * OBS + lane * 2);
    float v0 = xv.x * d2, v1 = xv.y * d2;
    int e0 = rowptr[wv], e1 = rowptr[wv + 1];
    for (int e = e0; e < e1; ++e) {                      // wave-uniform loop
        int s = esrc[e];
        float c = coefs[e];
        float2 sv = *(const float2*)(x + (size_t)s * OBS + lane * 2);
        v0 += sv.x * c; v1 += sv.y * c;
    }
    ushort2 o; o.x = f2b(v0); o.y = f2b(v1);
    *(ushort2*)(aggbf + (size_t)wv * OBS + lane * 2) = o;
}

// ---------- fused GEMM1 + relu + MFMA epilogue (@M2) -> zacc ----------
__global__ __launch_bounds__(256) void k_gemm1_fused(const ushort* __restrict__ A,
                                                     const ushort* __restrict__ Bt,
                                                     const float* __restrict__ bias,
                                                     const ushort* __restrict__ M2bf,
                                                     float* __restrict__ zacc,
                                                     int M) {
    __shared__ ushort buf[128 * 136 + 16 * 128];         // 38912 B
    ushort* As    = buf;
    ushort* Bs    = buf + 4096;
    ushort* stage = buf;
    ushort* M2t   = buf + 128 * 136;

    const int t = threadIdx.x;
    const int bm = blockIdx.x, bn = blockIdx.y;
    const int lane = t & 63, wv = t >> 6;
    const int wm = (wv & 1) * 64, wn = (wv >> 1) * 64;
    const int l16 = lane & 15, kg = (lane >> 4) * 8;
    const int r0 = t >> 2;
    const int c0 = (t & 3) << 3;

    if (t < 128) {
        ushort4 a = *(const ushort4*)(M2bf + (size_t)(bn * 128 + t) * ACTD);
        ushort4 b = *(const ushort4*)(M2bf + (size_t)(bn * 128 + t) * ACTD + 4);
        M2t[0 * 128 + t] = a.x; M2t[1 * 128 + t] = a.y;
        M2t[2 * 128 + t] = a.z; M2t[3 * 128 + t] = a.w;
        M2t[4 * 128 + t] = b.x; M2t[5 * 128 + t] = b.y;
        M2t[6 * 128 + t] = b.z; M2t[7 * 128 + t] = b.w;
        #pragma unroll
        for (int j = 8; j < 16; ++j) M2t[j * 128 + t] = 0;
    }

    f32x4 acc[4][4];
    #pragma unroll
    for (int i = 0; i < 4; ++i)
        #pragma unroll
        for (int j = 0; j < 4; ++j)
            acc[i][j] = (f32x4){0.f, 0.f, 0.f, 0.f};

    for (int kt = 0; kt < OBS; kt += 32) {
        if (kt) __syncthreads();
        #pragma unroll
        for (int rd = 0; rd < 2; ++rd) {
            int r = r0 + rd * 64;
            int gr = bm * 128 + r;
            uint4 va = make_uint4(0, 0, 0, 0);
            if (gr < M) va = *(const uint4*)(A + (size_t)gr * OBS + kt + c0);
            *(uint4*)(As + r * 32 + c0) = va;
            int gn = bn * 128 + r;
            uint4 vb = *(const uint4*)(Bt + (size_t)gn * OBS + kt + c0);
            *(uint4*)(Bs + r * 32 + c0) = vb;
        }
        __syncthreads();
        bf16x8 af[4], bfr[4];
        #pragma unroll
        for (int i = 0; i < 4; ++i)
            af[i] = *(const bf16x8*)(As + (wm + i * 16 + l16) * 32 + kg);
        #pragma unroll
        for (int j = 0; j < 4; ++j)
            bfr[j] = *(const bf16x8*)(Bs + (wn + j * 16 + l16) * 32 + kg);
        #pragma unroll
        for (int i = 0; i < 4; ++i)
            #pragma unroll
            for (int j = 0; j < 4; ++j)
                acc[i][j] = __builtin_amdgcn_mfma_f32_16x16x32_bf16(af[i], bfr[j], acc[i][j], 0, 0, 0);
    }
    __syncthreads();                                     // As/Bs dead; stage takes over

    #pragma unroll
    for (int i = 0; i < 4; ++i) {
        int rowb = wm + i * 16 + (lane >> 4) * 4;
        #pragma unroll
        for (int j = 0; j < 4; ++j) {
            int col = wn + j * 16 + l16;
            float bj = bias[bn * 128 + col];
            #pragma unroll
            for (int r = 0; r < 4; ++r)
                stage[(rowb + r) * 136 + col] = f2b(fmaxf(acc[i][j][r] + bj, 0.0f));
        }
    }
    __syncthreads();

    #pragma unroll
    for (int st = 0; st < 2; ++st) {
        int row0 = wv * 32 + st * 16;
        f32x4 z = (f32x4){0.f, 0.f, 0.f, 0.f};
        #pragma unroll
        for (int kt = 0; kt < 128; kt += 32) {
            bf16x8 a = *(const bf16x8*)(stage + (row0 + l16) * 136 + kt + kg);
            bf16x8 b = *(const bf16x8*)(M2t + l16 * 128 + kt + kg);
            z = __builtin_amdgcn_mfma_f32_16x16x32_bf16(a, b, z, 0, 0, 0);
        }
        if (l16 < ACTD) {
            int rowb = bm * 128 + row0 + (lane >> 4) * 4;
            #pragma unroll
            for (int r = 0; r < 4; ++r)
                if (rowb + r < M)
                    atomicAdd(&zacc[(size_t)(rowb + r) * ACTD + l16], z[r]);
        }
    }
}

// ---------- z-aggregation (gather) + tanh + hierarchical pool ----------
// 1024 threads = 128 nodes/block; LDS per-graph partials, range-flush
// (batch is sorted, so a block spans ~1-2 graphs -> ~16-24 global atomics/block)
__global__ __launch_bounds__(1024) void k_zfinal(const float* __restrict__ zacc,
                                                 const float* __restrict__ dinv,
                                                 const int* __restrict__ rowptr,
                                                 const int* __restrict__ esrc,
                                                 const float* __restrict__ coefs,
                                                 const float* __restrict__ b2l,
                                                 const int* __restrict__ batch,
                                                 float* __restrict__ pool,
                                                 float* __restrict__ cnt, int n) {
    __shared__ float part[NGR * ACTD];                   // 512 f32
    __shared__ int   partc[NGR];
    int t = threadIdx.x;
    if (t < NGR * ACTD) part[t] = 0.0f;
    if (t < NGR) partc[t] = 0;
    __syncthreads();

    int idx = blockIdx.x * 1024 + t;                     // (node, dim) space
    int i = idx >> 3, j = idx & 7;
    if (i < n) {
        float d = dinv[i];
        float v = zacc[idx] * d * d;
        int e0 = rowptr[i], e1 = rowptr[i + 1];
        for (int e = e0; e < e1; ++e)
            v += coefs[e] * zacc[(size_t)esrc[e] * ACTD + j];
        float tz = tanhf(v + b2l[j]);
        int g = cix(batch[i], NGR);
        atomicAdd(&part[g * ACTD + j], tz);              // LDS atomic
        if (j == 0) atomicAdd(&partc[g], 1);
    }
    __syncthreads();

    int i0 = (blockIdx.x * 1024) >> 3;
    int i1 = (blockIdx.x * 1024 + 1023) >> 3;
    if (i0 >= n) return;
    if (i1 >= n) i1 = n - 1;
    int g0 = cix(batch[i0], NGR), g1 = cix(batch[i1], NGR);
    int ng = g1 - g0 + 1;                                // sorted batch => contiguous range
    if (t < ng * ACTD)
        atomicAdd(&pool[g0 * ACTD + t], part[g0 * ACTD + t]);
    if (t < ng) {
        int c = partc[g0 + t];
        if (c) atomicAdd(&cnt[g0 + t], (float)c);
    }
}

__global__ void k_final(const float* __restrict__ pool, const float* __restrict__ cnt,
                        float* __restrict__ out, int total) {
    int i = blockIdx.x * 256 + threadIdx.x;
    if (i < total) out[i] = pool[i] / fmaxf(cnt[i >> 3], 1.0f);
}

// ---------- launch ----------
extern "C" void kernel_launch(void* const* d_in, const int* in_sizes, int n_in,
                              void* d_out, int out_size, void* d_ws, size_t ws_size,
                              hipStream_t stream) {
    const float* x   = (const float*)d_in[0];
    const int*   ei  = (const int*)d_in[1];
    const int*   bat = (const int*)d_in[2];
    const float* W1  = (const float*)d_in[3];
    const float* b1  = (const float*)d_in[4];
    const float* W2  = (const float*)d_in[5];
    const float* b2v = (const float*)d_in[6];
    const float* Wl  = (const float*)d_in[7];
    const float* bl  = (const float*)d_in[8];
    float* out = (float*)d_out;

    const int N = NNODES, E = NEDGES;
    const int* src = ei;
    const int* dst = ei + E;

    // workspace layout — ~4.3 MB total
    char* ws = (char*)d_ws;
    size_t off = 0;
    float*  pool   = (float*)(ws + off); off += 2048;
    float*  cnt    = (float*)(ws + off); off += 256;
    float*  dinv   = (float*)(ws + off); off += 40192;                   // N f32
    int*    degi   = (int*)(ws + off);   off += 40192;                   // N i32
    int*    rowptr = (int*)(ws + off);   off += 40448;                   // N+1 i32
    int*    cursor = (int*)(ws + off);   off += 40192;                   // N i32
    int*    esrc   = (int*)(ws + off);   off += (size_t)E * 4;           // 320000
    float*  coefs  = (float*)(ws + off); off += (size_t)E * 4;           // 320000
    float*  b2l    = (float*)(ws + off); off += 256;
    ushort* M2bf   = (ushort*)(ws + off); off += (size_t)HID * ACTD * 2; // 16384
    ushort* Wt1    = (ushort*)(ws + off); off += (size_t)HID * OBS * 2;  // 262144
    float*  zacc   = (float*)(ws + off); off += (size_t)N * ACTD * 4;    // 320000
    ushort* aggbf  = (ushort*)(ws + off); off += (size_t)N * OBS * 2;    // 2560000

    // 1. degree + dinv + CSR build
    k_init<<<(N * ACTD + 255) / 256, 256, 0, stream>>>(degi, zacc, pool, cnt, N);
    k_count<<<(E + 255) / 256, 256, 0, stream>>>(dst, degi, E);
    k_scan<<<1, 1024, 0, stream>>>(degi, rowptr, cursor, dinv);
    k_fill<<<(E + 255) / 256, 256, 0, stream>>>(src, dst, dinv, cursor, esrc, coefs, E);

    // 2. weight prep (transpose W1 + M2 = W2@Wl + b2l, one fused launch)
    k_weights<<<128 + ((HID + 1) * 64 + 255) / 256, 256, 0, stream>>>(
        W1, W2, Wl, b2v, bl, Wt1, M2bf, b2l);

    // 3. layer-1 aggregation (gather) -> bf16
    k_aggx<<<(N * 64 + 255) / 256, 256, 0, stream>>>(x, dinv, rowptr, esrc, coefs, aggbf, N);

    // 4. fused GEMM1 + relu + @M2 -> zacc
    k_gemm1_fused<<<dim3((N + 127) / 128, HID / 128), 256, 0, stream>>>(
        aggbf, Wt1, b1, M2bf, zacc, N);

    // 5. z-aggregation (gather) + tanh + hierarchical pool, finalize
    k_zfinal<<<(N * ACTD + 1023) / 1024, 1024, 0, stream>>>(
        zacc, dinv, rowptr, esrc, coefs, b2l, bat, pool, cnt, N);
    k_final<<<2, 256, 0, stream>>>(pool, cnt, out, NGR * ACTD);
}

// Round 8
// 135.532 us; speedup vs baseline: 1.5326x; 1.0262x over previous
//
#include <hip/hip_runtime.h>
#include <hip/hip_bf16.h>

// ---------- constants (problem-fixed) ----------
#define NNODES 10000
#define NEDGES 80000
#define OBS    128
#define HID    1024
#define ACTD   8
#define NGR    64

typedef __bf16 bf16x8 __attribute__((ext_vector_type(8)));
typedef float  f32x4  __attribute__((ext_vector_type(4)));
typedef const __attribute__((address_space(1))) unsigned int gl_u32;
typedef __attribute__((address_space(3))) unsigned int lds_u32;

__device__ __forceinline__ ushort f2b(float f) {       // f32 -> bf16 (RNE)
    union { float f; unsigned int i; } v; v.f = f;
    unsigned int lsb = (v.i >> 16) & 1u;
    unsigned int r = v.i + 0x7fffu + lsb;
    return (ushort)(r >> 16);
}
__device__ __forceinline__ int cix(int v, int hi) {    // clamp index to [0, hi)
    return v < 0 ? 0 : (v >= hi ? hi - 1 : v);
}

// ---------- fused prep: zero accumulators + weight prep, block-partitioned ----------
//  blocks [0,128):   transpose+cast W1 [OBS x HID] -> Wt1 [HID x OBS] bf16
//  blocks [128,385): M2bf[i][:] = bf16(W2[i,:] @ Wl); row HID -> b2l = b2@Wl + bl
//  blocks [385,698): zero zacc / pool / cnt / degi
__global__ __launch_bounds__(256) void k_prep(const float* __restrict__ W1,
                                              const float* __restrict__ W2,
                                              const float* __restrict__ Wl,
                                              const float* __restrict__ b2,
                                              const float* __restrict__ bl,
                                              ushort* __restrict__ Wt1,
                                              ushort* __restrict__ M2bf,
                                              float* __restrict__ b2l,
                                              float* __restrict__ zacc,
                                              float* __restrict__ pool,
                                              float* __restrict__ cnt,
                                              int* __restrict__ degi) {
    int blk = blockIdx.x;
    if (blk >= 385) {
        int idx = (blk - 385) * 256 + threadIdx.x;
        if (idx < NNODES * ACTD) zacc[idx] = 0.0f;
        if (idx < NGR * ACTD) pool[idx] = 0.0f;
        if (idx < NGR) cnt[idx] = 0.0f;
        if (idx < NNODES) degi[idx] = 0;
        return;
    }
    if (blk < 128) {
        __shared__ float tile[32][33];
        int bx = (blk & 31) * 32, by = (blk >> 5) * 32;  // bx over HID, by over OBS
        int tx = threadIdx.x & 31, ty = threadIdx.x >> 5;
        #pragma unroll
        for (int i = 0; i < 32; i += 8)
            tile[ty + i][tx] = W1[(size_t)(by + ty + i) * HID + bx + tx];
        __syncthreads();
        #pragma unroll
        for (int i = 0; i < 32; i += 8)
            Wt1[(size_t)(bx + ty + i) * OBS + by + tx] = f2b(tile[tx][ty + i]);
        return;
    }
    int wvid = ((blk - 128) * 256 + (int)threadIdx.x) >> 6;
    int lane = threadIdx.x & 63;
    if (wvid > HID) return;
    const float* row = (wvid == HID) ? b2 : (W2 + (size_t)wvid * HID);
    float acc[ACTD];
    #pragma unroll
    for (int j = 0; j < ACTD; ++j) acc[j] = 0.0f;
    for (int it = 0; it < HID / 64; ++it) {
        int k = it * 64 + lane;
        float w2v = row[k];
        float4 a = *(const float4*)(Wl + (size_t)k * ACTD);
        float4 b = *(const float4*)(Wl + (size_t)k * ACTD + 4);
        acc[0] += w2v * a.x; acc[1] += w2v * a.y; acc[2] += w2v * a.z; acc[3] += w2v * a.w;
        acc[4] += w2v * b.x; acc[5] += w2v * b.y; acc[6] += w2v * b.z; acc[7] += w2v * b.w;
    }
    #pragma unroll
    for (int off = 32; off > 0; off >>= 1)
        #pragma unroll
        for (int j = 0; j < ACTD; ++j)
            acc[j] += __shfl_down(acc[j], off);
    if (lane == 0) {
        if (wvid == HID) {
            #pragma unroll
            for (int j = 0; j < ACTD; ++j) b2l[j] = acc[j] + bl[j];
        } else {
            #pragma unroll
            for (int j = 0; j < ACTD; ++j) M2bf[wvid * ACTD + j] = f2b(acc[j]);
        }
    }
}

__global__ void k_count(const int* __restrict__ dst, int* degi, int e) {
    int i = blockIdx.x * 256 + threadIdx.x;
    if (i < e) atomicAdd(&degi[cix(dst[i], NNODES)], 1);
}

// single-block scan via wave shuffles (2 barriers) -> rowptr (N+1) + cursor + dinv
__global__ __launch_bounds__(1024) void k_scan(const int* __restrict__ degi,
                                               int* rowptr, int* cursor, float* dinv) {
    __shared__ int wsum[16];
    int t = threadIdx.x, lane = t & 63, w = t >> 6;
    int base = t * 10;                                   // 10240 >= NNODES
    int local[10];
    int s = 0;
    #pragma unroll
    for (int k = 0; k < 10; ++k) {
        int i = base + k;
        int v = 0;
        if (i < NNODES) {
            v = degi[i];
            dinv[i] = rsqrtf((float)(v + 1));            // +1 self-loop
        }
        local[k] = s; s += v;
    }
    int sc = s;                                          // inclusive wave scan
    #pragma unroll
    for (int off = 1; off < 64; off <<= 1) {
        int u = __shfl_up(sc, off);
        if (lane >= off) sc += u;
    }
    if (lane == 63) wsum[w] = sc;
    __syncthreads();
    if (w == 0 && lane < 16) {
        int v = wsum[lane];
        #pragma unroll
        for (int off = 1; off < 16; off <<= 1) {
            int u = __shfl_up(v, off);
            if (lane >= off) v += u;
        }
        wsum[lane] = v;                                  // inclusive wave totals
    }
    __syncthreads();
    int excl = ((w == 0) ? 0 : wsum[w - 1]) + (sc - s);  // exclusive thread offset
    #pragma unroll
    for (int k = 0; k < 10; ++k) {
        int i = base + k;
        if (i < NNODES) { rowptr[i] = excl + local[k]; cursor[i] = excl + local[k]; }
    }
    if (t == 0) rowptr[NNODES] = wsum[15];
}

// bucket edges by dst: sorted src + coef
__global__ void k_fill(const int* __restrict__ src, const int* __restrict__ dst,
                       const float* __restrict__ dinv, int* cursor,
                       int* __restrict__ esrc, float* __restrict__ coefs, int e) {
    int i = blockIdx.x * 256 + threadIdx.x;
    if (i >= e) return;
    int s = cix(src[i], NNODES), d = cix(dst[i], NNODES);
    int pos = atomicAdd(&cursor[d], 1);
    esrc[pos] = s;
    coefs[pos] = dinv[s] * dinv[d];
}

// ---------- layer-1 aggregation: CSR gather, one wave per node, edges x2 unrolled ----------
__global__ void k_aggx(const float* __restrict__ x, const float* __restrict__ dinv,
                       const int* __restrict__ rowptr, const int* __restrict__ esrc,
                       const float* __restrict__ coefs, ushort* __restrict__ aggbf, int n) {
    int wv = (blockIdx.x * 256 + threadIdx.x) >> 6;
    int lane = threadIdx.x & 63;
    if (wv >= n) return;
    float d = dinv[wv], d2 = d * d;
    float2 xv = *(const float2*)(x + (size_t)wv * OBS + lane * 2);
    float v0 = xv.x * d2, v1 = xv.y * d2;
    int e = rowptr[wv], e1 = rowptr[wv + 1];
    for (; e + 2 <= e1; e += 2) {                        // wave-uniform, 2x MLP
        int s0 = esrc[e], s1 = esrc[e + 1];
        float c0 = coefs[e], c1 = coefs[e + 1];
        float2 a = *(const float2*)(x + (size_t)s0 * OBS + lane * 2);
        float2 b = *(const float2*)(x + (size_t)s1 * OBS + lane * 2);
        v0 += a.x * c0 + b.x * c1;
        v1 += a.y * c0 + b.y * c1;
    }
    if (e < e1) {
        int s0 = esrc[e];
        float c0 = coefs[e];
        float2 a = *(const float2*)(x + (size_t)s0 * OBS + lane * 2);
        v0 += a.x * c0; v1 += a.y * c0;
    }
    ushort2 o; o.x = f2b(v0); o.y = f2b(v1);
    *(ushort2*)(aggbf + (size_t)wv * OBS + lane * 2) = o;
}

// ---------- fused GEMM1 + relu + MFMA epilogue (@M2) -> zacc ----------
// block 256 (4 waves), tile 128x128, K=OBS=128, BK=64, async global->LDS staging.
// LDS union: As(8192h)+Bs(8192h) overlapped by stage(128x136h), + M2t(16x128h) = 38912 B
__global__ __launch_bounds__(256) void k_gemm1_fused(const ushort* __restrict__ A,
                                                     const ushort* __restrict__ Bt,
                                                     const float* __restrict__ bias,
                                                     const ushort* __restrict__ M2bf,
                                                     float* __restrict__ zacc,
                                                     int M) {
    __shared__ ushort buf[128 * 136 + 16 * 128];         // 38912 B
    ushort* As    = buf;                                 // hw [0, 8192)
    ushort* Bs    = buf + 8192;                          // hw [8192, 16384)
    ushort* stage = buf;                                 // hw [0, 17408) after K-loop
    ushort* M2t   = buf + 128 * 136;                     // hw [17408, 19456)

    const int t = threadIdx.x;
    const int bm = blockIdx.x, bn = blockIdx.y;
    const int lane = t & 63, wv = t >> 6;
    const int wm = (wv & 1) * 64, wn = (wv >> 1) * 64;
    const int l16 = lane & 15, kg = (lane >> 4) * 8;

    if (t < 128) {
        ushort4 a = *(const ushort4*)(M2bf + (size_t)(bn * 128 + t) * ACTD);
        ushort4 b = *(const ushort4*)(M2bf + (size_t)(bn * 128 + t) * ACTD + 4);
        M2t[0 * 128 + t] = a.x; M2t[1 * 128 + t] = a.y;
        M2t[2 * 128 + t] = a.z; M2t[3 * 128 + t] = a.w;
        M2t[4 * 128 + t] = b.x; M2t[5 * 128 + t] = b.y;
        M2t[6 * 128 + t] = b.z; M2t[7 * 128 + t] = b.w;
        #pragma unroll
        for (int j = 8; j < 16; ++j) M2t[j * 128 + t] = 0;
    }

    f32x4 acc[4][4];
    #pragma unroll
    for (int i = 0; i < 4; ++i)
        #pragma unroll
        for (int j = 0; j < 4; ++j)
            acc[i][j] = (f32x4){0.f, 0.f, 0.f, 0.f};

    const int rs = t >> 3;                               // 0..31
    const int cs = (t & 7) * 8;                          // hw col, 16B chunks
    #pragma unroll
    for (int kt = 0; kt < OBS; kt += 64) {
        #pragma unroll
        for (int p = 0; p < 4; ++p) {                    // 32 rows/pass
            int r = rs + p * 32;
            int gr = bm * 128 + r; if (gr >= M) gr = M - 1;   // clamp (row discarded later)
            __builtin_amdgcn_global_load_lds(
                (gl_u32*)(A + (size_t)gr * OBS + kt + cs),
                (lds_u32*)(As + r * 64 + cs), 16, 0, 0);
            int gn = bn * 128 + r;
            __builtin_amdgcn_global_load_lds(
                (gl_u32*)(Bt + (size_t)gn * OBS + kt + cs),
                (lds_u32*)(Bs + r * 64 + cs), 16, 0, 0);
        }
        __syncthreads();                                 // drains vmcnt + barrier
        #pragma unroll
        for (int k2 = 0; k2 < 64; k2 += 32) {
            bf16x8 af[4], bfr[4];
            #pragma unroll
            for (int i = 0; i < 4; ++i)
                af[i] = *(const bf16x8*)(As + (wm + i * 16 + l16) * 64 + k2 + kg);
            #pragma unroll
            for (int j = 0; j < 4; ++j)
                bfr[j] = *(const bf16x8*)(Bs + (wn + j * 16 + l16) * 64 + k2 + kg);
            #pragma unroll
            for (int i = 0; i < 4; ++i)
                #pragma unroll
                for (int j = 0; j < 4; ++j)
                    acc[i][j] = __builtin_amdgcn_mfma_f32_16x16x32_bf16(af[i], bfr[j], acc[i][j], 0, 0, 0);
        }
        __syncthreads();                                 // LDS reads done before overwrite
    }

    // relu(acc + bias) -> stage bf16; C/D layout: col=lane&15, row=(lane>>4)*4+reg
    #pragma unroll
    for (int i = 0; i < 4; ++i) {
        int rowb = wm + i * 16 + (lane >> 4) * 4;
        #pragma unroll
        for (int j = 0; j < 4; ++j) {
            int col = wn + j * 16 + l16;
            float bj = bias[bn * 128 + col];
            #pragma unroll
            for (int r = 0; r < 4; ++r)
                stage[(rowb + r) * 136 + col] = f2b(fmaxf(acc[i][j][r] + bj, 0.0f));
        }
    }
    __syncthreads();

    #pragma unroll
    for (int st = 0; st < 2; ++st) {
        int row0 = wv * 32 + st * 16;
        f32x4 z = (f32x4){0.f, 0.f, 0.f, 0.f};
        #pragma unroll
        for (int kt = 0; kt < 128; kt += 32) {
            bf16x8 a = *(const bf16x8*)(stage + (row0 + l16) * 136 + kt + kg);
            bf16x8 b = *(const bf16x8*)(M2t + l16 * 128 + kt + kg);
            z = __builtin_amdgcn_mfma_f32_16x16x32_bf16(a, b, z, 0, 0, 0);
        }
        if (l16 < ACTD) {
            int rowb = bm * 128 + row0 + (lane >> 4) * 4;
            #pragma unroll
            for (int r = 0; r < 4; ++r)
                if (rowb + r < M)
                    atomicAdd(&zacc[(size_t)(rowb + r) * ACTD + l16], z[r]);
        }
    }
}

// ---------- z-aggregation (gather) + tanh + hierarchical pool ----------
__global__ __launch_bounds__(1024) void k_zfinal(const float* __restrict__ zacc,
                                                 const float* __restrict__ dinv,
                                                 const int* __restrict__ rowptr,
                                                 const int* __restrict__ esrc,
                                                 const float* __restrict__ coefs,
                                                 const float* __restrict__ b2l,
                                                 const int* __restrict__ batch,
                                                 float* __restrict__ pool,
                                                 float* __restrict__ cnt, int n) {
    __shared__ float part[NGR * ACTD];
    __shared__ int   partc[NGR];
    int t = threadIdx.x;
    if (t < NGR * ACTD) part[t] = 0.0f;
    if (t < NGR) partc[t] = 0;
    __syncthreads();

    int idx = blockIdx.x * 1024 + t;
    int i = idx >> 3, j = idx & 7;
    if (i < n) {
        float d = dinv[i];
        float v = zacc[idx] * d * d;
        int e0 = rowptr[i], e1 = rowptr[i + 1];
        for (int e = e0; e < e1; ++e)
            v += coefs[e] * zacc[(size_t)esrc[e] * ACTD + j];
        float tz = tanhf(v + b2l[j]);
        int g = cix(batch[i], NGR);
        atomicAdd(&part[g * ACTD + j], tz);
        if (j == 0) atomicAdd(&partc[g], 1);
    }
    __syncthreads();

    int i0 = (blockIdx.x * 1024) >> 3;
    int i1 = (blockIdx.x * 1024 + 1023) >> 3;
    if (i0 >= n) return;
    if (i1 >= n) i1 = n - 1;
    int g0 = cix(batch[i0], NGR), g1 = cix(batch[i1], NGR);
    int ng = g1 - g0 + 1;                                // sorted batch => contiguous
    if (t < ng * ACTD)
        atomicAdd(&pool[g0 * ACTD + t], part[g0 * ACTD + t]);
    if (t < ng) {
        int c = partc[g0 + t];
        if (c) atomicAdd(&cnt[g0 + t], (float)c);
    }
}

__global__ void k_final(const float* __restrict__ pool, const float* __restrict__ cnt,
                        float* __restrict__ out, int total) {
    int i = blockIdx.x * 256 + threadIdx.x;
    if (i < total) out[i] = pool[i] / fmaxf(cnt[i >> 3], 1.0f);
}

// ---------- launch ----------
extern "C" void kernel_launch(void* const* d_in, const int* in_sizes, int n_in,
                              void* d_out, int out_size, void* d_ws, size_t ws_size,
                              hipStream_t stream) {
    const float* x   = (const float*)d_in[0];
    const int*   ei  = (const int*)d_in[1];
    const int*   bat = (const int*)d_in[2];
    const float* W1  = (const float*)d_in[3];
    const float* b1  = (const float*)d_in[4];
    const float* W2  = (const float*)d_in[5];
    const float* b2v = (const float*)d_in[6];
    const float* Wl  = (const float*)d_in[7];
    const float* bl  = (const float*)d_in[8];
    float* out = (float*)d_out;

    const int N = NNODES, E = NEDGES;
    const int* src = ei;
    const int* dst = ei + E;

    // workspace layout — ~4.3 MB total (all offsets multiples of 256 B)
    char* ws = (char*)d_ws;
    size_t off = 0;
    float*  pool   = (float*)(ws + off); off += 2048;
    float*  cnt    = (float*)(ws + off); off += 256;
    float*  dinv   = (float*)(ws + off); off += 40192;                   // N f32
    int*    degi   = (int*)(ws + off);   off += 40192;                   // N i32
    int*    rowptr = (int*)(ws + off);   off += 40448;                   // N+1 i32
    int*    cursor = (int*)(ws + off);   off += 40192;                   // N i32
    int*    esrc   = (int*)(ws + off);   off += (size_t)E * 4;           // 320000
    float*  coefs  = (float*)(ws + off); off += (size_t)E * 4;           // 320000
    float*  b2l    = (float*)(ws + off); off += 256;
    ushort* M2bf   = (ushort*)(ws + off); off += (size_t)HID * ACTD * 2; // 16384
    ushort* Wt1    = (ushort*)(ws + off); off += (size_t)HID * OBS * 2;  // 262144
    float*  zacc   = (float*)(ws + off); off += (size_t)N * ACTD * 4;    // 320000
    ushort* aggbf  = (ushort*)(ws + off); off += (size_t)N * OBS * 2;    // 2560000

    // 1. fused zero + weight prep
    k_prep<<<698, 256, 0, stream>>>(W1, W2, Wl, b2v, bl, Wt1, M2bf, b2l,
                                    zacc, pool, cnt, degi);
    // 2-4. degree, scan(+dinv), CSR fill
    k_count<<<(E + 255) / 256, 256, 0, stream>>>(dst, degi, E);
    k_scan<<<1, 1024, 0, stream>>>(degi, rowptr, cursor, dinv);
    k_fill<<<(E + 255) / 256, 256, 0, stream>>>(src, dst, dinv, cursor, esrc, coefs, E);

    // 5. layer-1 aggregation (gather) -> bf16
    k_aggx<<<(N * 64 + 255) / 256, 256, 0, stream>>>(x, dinv, rowptr, esrc, coefs, aggbf, N);

    // 6. fused GEMM1 + relu + @M2 -> zacc
    k_gemm1_fused<<<dim3((N + 127) / 128, HID / 128), 256, 0, stream>>>(
        aggbf, Wt1, b1, M2bf, zacc, N);

    // 7. z-aggregation (gather) + tanh + hierarchical pool, finalize
    k_zfinal<<<(N * ACTD + 1023) / 1024, 1024, 0, stream>>>(
        zacc, dinv, rowptr, esrc, coefs, b2l, bat, pool, cnt, N);
    k_final<<<2, 256, 0, stream>>>(pool, cnt, out, NGR * ACTD);
}